// Round 3
// baseline (2384.367 us; speedup 1.0000x reference)
//
#include <hip/hip_runtime.h>
#include <math.h>

constexpr int CN = 4096, CHH = 8, CD = 64, CM = 128;
constexpr int V1P_OFF = 16 * 4096 * 8 * 64;             // 33554432 floats
constexpr int V2P_OFF = V1P_OFF + 16 * 4096 * 8 * 128;  // 100663296 floats
constexpr float KSCALE = 0.35355339059327373f;          // 64^-0.25 (tau=1)
constexpr float KRATIO = 0.08838834764831843f;          // 1/sqrt(128)
constexpr float KEPS   = 1e-6f;

__device__ __forceinline__ float dot4(float4 a, float4 b) {
  return fmaf(a.x, b.x, fmaf(a.y, b.y, fmaf(a.z, b.z, a.w * b.w)));
}
__device__ __forceinline__ float4 scl4(float4 a, float s) {
  return make_float4(a.x * s, a.y * s, a.z * s, a.w * s);
}
__device__ __forceinline__ void fma4(float4& a, float s, float4 b) {
  a.x = fmaf(s, b.x, a.x); a.y = fmaf(s, b.y, a.y);
  a.z = fmaf(s, b.z, a.z); a.w = fmaf(s, b.w, a.w);
}
__device__ __forceinline__ float expv(float s, float c) {
  return KRATIO * (__expf(s + c) + KEPS);
}

// ---- K1: per-row max of key data_dash. 1 row/thread in regs, proj via SGPR.
__global__ __launch_bounds__(256) void k1_maxdd(
    const float* __restrict__ nv2, const float* __restrict__ proj,
    float* __restrict__ partmax) {
  const int bh = blockIdx.x >> 4, ch = blockIdx.x & 15;
  const int b = bh >> 3, h = bh & 7;
  const int n = ch * 256 + threadIdx.x;
  const float4* a = (const float4*)(nv2 + (size_t)((b * CN + n) * CHH + h) * CD);
  float4 v[16];
#pragma unroll
  for (int q = 0; q < 16; q++) v[q] = scl4(a[q], KSCALE);
  float mx = -1e30f;
  for (int j = 0; j < 128; j += 2) {
    const float4* p0 = (const float4*)(proj + j * 64);
    const float4* p1 = p0 + 16;
    float a0 = 0.f, a1 = 0.f, b0 = 0.f, b1 = 0.f;
#pragma unroll
    for (int q = 0; q < 16; q += 2) {
      a0 += dot4(v[q], p0[q]);     a1 += dot4(v[q + 1], p0[q + 1]);
      b0 += dot4(v[q], p1[q]);     b1 += dot4(v[q + 1], p1[q + 1]);
    }
    mx = fmaxf(mx, fmaxf(a0 + a1, b0 + b1));
  }
  __shared__ float red[256];
  red[threadIdx.x] = mx;
  __syncthreads();
  for (int s = 128; s > 0; s >>= 1) {
    if ((int)threadIdx.x < s) red[threadIdx.x] = fmaxf(red[threadIdx.x], red[threadIdx.x + s]);
    __syncthreads();
  }
  if (threadIdx.x == 0) partmax[blockIdx.x] = red[0];
}

// ---- K1b: reduce 16 partials -> per-bh max
__global__ void k1b_reduce(const float* __restrict__ partmax, float* __restrict__ wmax) {
  const int bh = threadIdx.x;  // 128 threads
  float m = -1e30f;
#pragma unroll
  for (int c = 0; c < 16; c++) m = fmaxf(m, partmax[bh * 16 + c]);
  wmax[bh] = m;
}

// ---- K2: v2p = ratio*(exp(dd - diag - mx_bh)+eps). 1 row/thread, 4x32 feats.
__global__ __launch_bounds__(256) void k2_v2p(
    const float* __restrict__ nv2, const float* __restrict__ proj,
    const float* __restrict__ wmax, float* __restrict__ v2p) {
  const int bh = blockIdx.x >> 4, ch = blockIdx.x & 15;
  const int b = bh >> 3, h = bh & 7;
  const int n = ch * 256 + threadIdx.x;
  const size_t r = (size_t)((b * CN + n) * CHH + h);
  const float4* a = (const float4*)(nv2 + r * CD);
  float4 v[16];
#pragma unroll
  for (int q = 0; q < 16; q++) v[q] = scl4(a[q], KSCALE);
  float diag = 0.f;
#pragma unroll
  for (int q = 0; q < 16; q++) diag += dot4(v[q], v[q]);
  const float c = -(0.5f * diag + wmax[bh]);
  float4* o = (float4*)(v2p + r * CM);
  for (int jb = 0; jb < 4; jb++) {
    float s[32];
#pragma unroll
    for (int jj = 0; jj < 32; jj += 2) {
      const float4* p0 = (const float4*)(proj + (jb * 32 + jj) * 64);
      const float4* p1 = p0 + 16;
      float a0 = 0.f, a1 = 0.f, b0 = 0.f, b1 = 0.f;
#pragma unroll
      for (int q = 0; q < 16; q += 2) {
        a0 += dot4(v[q], p0[q]);     a1 += dot4(v[q + 1], p0[q + 1]);
        b0 += dot4(v[q], p1[q]);     b1 += dot4(v[q + 1], p1[q + 1]);
      }
      s[jj] = a0 + a1; s[jj + 1] = b0 + b1;
    }
#pragma unroll
    for (int jj = 0; jj < 8; jj++)
      o[jb * 8 + jj] = make_float4(expv(s[jj * 4 + 0], c), expv(s[jj * 4 + 1], c),
                                   expv(s[jj * 4 + 2], c), expv(s[jj * 4 + 3], c));
  }
}

// ---- K3: partial v2x = v2p^T @ x. lane=j, acc[64 d] regs, x-row via SGPR.
__global__ __launch_bounds__(256) void k3_v2x(
    const float* __restrict__ v2p, const float* __restrict__ x,
    float* __restrict__ part, float* __restrict__ vsumpart) {
  const int bh = blockIdx.x >> 3, ch = blockIdx.x & 7;
  const int b = bh >> 3, h = bh & 7;
  const int wave = threadIdx.x >> 6, lane = threadIdx.x & 63;
  const int jlane = (wave & 1) * 64 + lane;       // 0..127
  const int nhalf = wave >> 1;                    // 0/1
  const int nbeg = ch * 512 + nhalf * 256;
  float4 acc4[16];
#pragma unroll
  for (int q = 0; q < 16; q++) acc4[q] = make_float4(0.f, 0.f, 0.f, 0.f);
  float vs = 0.f;
  for (int t = 0; t < 256; t += 2) {
    const int n1 = nbeg + t, n2 = n1 + 1;
    const size_t r1 = (size_t)((b * CN + n1) * CHH + h);
    const size_t r2 = (size_t)((b * CN + n2) * CHH + h);
    const float pv1 = v2p[r1 * CM + jlane];
    const float pv2 = v2p[r2 * CM + jlane];
    const float4* x1 = (const float4*)(x + r1 * CD);
    const float4* x2 = (const float4*)(x + r2 * CD);
#pragma unroll
    for (int q = 0; q < 16; q++) { fma4(acc4[q], pv1, x1[q]); fma4(acc4[q], pv2, x2[q]); }
    vs += pv1 + pv2;
  }
  const int pidx = blockIdx.x * 2 + nhalf;        // = bh*16 + ch*2 + nhalf
  float4* po = (float4*)(part + (size_t)pidx * 8192 + jlane * 64);
#pragma unroll
  for (int q = 0; q < 16; q++) po[q] = acc4[q];
  vsumpart[pidx * 128 + jlane] = vs;
}

// ---- K3b: reduce 16 partials -> v2x, v2sum  (grid EXACTLY 4160 blocks)
__global__ void k3b_reduce(const float* __restrict__ part, const float* __restrict__ vsumpart,
                           float* __restrict__ v2x, float* __restrict__ vsum) {
  const int i = blockIdx.x * 256 + threadIdx.x;   // covers 1048576 + 16384
  if (i < 1048576) {
    const int bh = i >> 13, r = i & 8191;
    float s = 0.f;
#pragma unroll
    for (int c = 0; c < 16; c++) s += part[(size_t)((bh * 16 + c)) * 8192 + r];
    v2x[i] = s;
  } else if (i < 1048576 + 16384) {               // bounds guard (r2 bug: OOB)
    const int k = i - 1048576, bh = k >> 7, j = k & 127;
    float s = 0.f;
#pragma unroll
    for (int c = 0; c < 16; c++) s += vsumpart[(bh * 16 + c) * 128 + j];
    vsum[k] = s;
  }
}

// ---- K4a: v1p. 2 waves split feature dim (wave-uniform halves -> SGPR proj),
//      dd[64]+v[64] regs (~150 VGPR, no spill), cross-wave max via LDS.
__global__ __launch_bounds__(256) void k4a_v1p(
    const float* __restrict__ nv1, const float* __restrict__ proj,
    float* __restrict__ v1p) {
  const int bh = blockIdx.x >> 5, ch = blockIdx.x & 31;
  const int b = bh >> 3, h = bh & 7;
  const int wave = threadIdx.x >> 6, lane = threadIdx.x & 63;
  const int fh = wave & 1;                        // feature half (wave-uniform)
  const int rloc = (wave >> 1) * 64 + lane;       // 0..127
  const int n = ch * 128 + rloc;
  const size_t r = (size_t)((b * CN + n) * CHH + h);
  const float4* a = (const float4*)(nv1 + r * CD);
  float4 v[16];
#pragma unroll
  for (int q = 0; q < 16; q++) v[q] = scl4(a[q], KSCALE);
  float diag = 0.f;
#pragma unroll
  for (int q = 0; q < 16; q++) diag += dot4(v[q], v[q]);
  float dd[64];
#pragma unroll
  for (int j = 0; j < 64; j += 2) {
    const float4* p0 = (const float4*)(proj + (fh * 64 + j) * 64);
    const float4* p1 = p0 + 16;
    float a0 = 0.f, a1 = 0.f, b0 = 0.f, b1 = 0.f;
#pragma unroll
    for (int q = 0; q < 16; q += 2) {
      a0 += dot4(v[q], p0[q]);     a1 += dot4(v[q + 1], p0[q + 1]);
      b0 += dot4(v[q], p1[q]);     b1 += dot4(v[q + 1], p1[q + 1]);
    }
    dd[j] = a0 + a1; dd[j + 1] = b0 + b1;
  }
  float m0 = -1e30f, m1 = -1e30f, m2 = -1e30f, m3 = -1e30f;
#pragma unroll
  for (int j = 0; j < 64; j += 4) {
    m0 = fmaxf(m0, dd[j]); m1 = fmaxf(m1, dd[j + 1]);
    m2 = fmaxf(m2, dd[j + 2]); m3 = fmaxf(m3, dd[j + 3]);
  }
  __shared__ float hm[2][128];
  hm[fh][rloc] = fmaxf(fmaxf(m0, m1), fmaxf(m2, m3));
  __syncthreads();
  const float c = -(0.5f * diag + fmaxf(hm[0][rloc], hm[1][rloc]));
  float4* o = (float4*)(v1p + r * CM + fh * 64);
#pragma unroll
  for (int q = 0; q < 16; q++)
    o[q] = make_float4(expv(dd[q * 4 + 0], c), expv(dd[q * 4 + 1], c),
                       expv(dd[q * 4 + 2], c), expv(dd[q * 4 + 3], c));
}

// ---- K4b: out0 = (v1p @ v2x) / (v1p . v2sum). LDS-transposed v1p tile,
//      v2x rows via SGPR, acc[64 d] regs, 256B coalesced out.
__global__ __launch_bounds__(256) void k4b_out(
    const float* __restrict__ v1p, const float* __restrict__ v2xg,
    const float* __restrict__ vsumg, float* __restrict__ out0) {
  __shared__ float tp[256 * 34];                  // [256 rows][32 j] pad 34
  const int bh = blockIdx.x >> 4, ch = blockIdx.x & 15;
  const int b = bh >> 3, h = bh & 7;
  const int nloc = threadIdx.x;                   // row handled by this thread
  const int nbase = ch * 256;
  float4 acc4[16];
#pragma unroll
  for (int q = 0; q < 16; q++) acc4[q] = make_float4(0.f, 0.f, 0.f, 0.f);
  float o2 = 0.f;
  for (int jb = 0; jb < 4; jb++) {
    __syncthreads();
    for (int i = threadIdx.x; i < 4096; i += 256) {
      const int row = i >> 4, q = i & 15;
      const float2 t = *((const float2*)(v1p + (size_t)((b * CN + nbase + row) * CHH + h) * CM + jb * 32) + q);
      *(float2*)(&tp[row * 34 + q * 2]) = t;
    }
    __syncthreads();
    for (int j = 0; j < 32; j++) {
      const int jg = jb * 32 + j;
      const float p = tp[nloc * 34 + j];
      const float4* xr = (const float4*)(v2xg + (size_t)bh * 8192 + jg * 64);
#pragma unroll
      for (int q = 0; q < 16; q++) fma4(acc4[q], p, xr[q]);
      o2 = fmaf(p, vsumg[bh * 128 + jg], o2);
    }
  }
  const float inv = 1.0f / o2;
  float4* ob = (float4*)(out0 + (size_t)((b * CN + nbase + nloc) * CHH + h) * CD);
#pragma unroll
  for (int q = 0; q < 16; q++) ob[q] = scl4(acc4[q], inv);
}

extern "C" void kernel_launch(void* const* d_in, const int* in_sizes, int n_in,
                              void* d_out, int out_size, void* d_ws, size_t ws_size,
                              hipStream_t stream) {
  (void)in_sizes; (void)n_in; (void)out_size; (void)ws_size;
  const float* x    = (const float*)d_in[0];
  const float* nv1  = (const float*)d_in[1];
  const float* nv2  = (const float*)d_in[2];
  const float* proj = (const float*)d_in[3];
  float* out  = (float*)d_out;
  float* out0 = out;
  float* v1p  = out + V1P_OFF;
  float* v2p  = out + V2P_OFF;

  // Scratch inside the v1p output region (dead before k4a writes v1p):
  float* part     = v1p;                  // 2048*8192 = 16,777,216 floats
  float* partmax  = v1p + 16777216;       // 2,048
  float* vsumpart = v1p + 16779264;       // 2048*128 = 262,144
  // Persistent scratch in ws (~4.3 MB): survives into k4b.
  float* ws   = (float*)d_ws;
  float* wmax = ws;                       // 128
  float* vsum = ws + 128;                 // 16,384
  float* v2x  = ws + 16512;               // 1,048,576

  k1_maxdd  <<<dim3(2048), dim3(256), 0, stream>>>(nv2, proj, partmax);
  k1b_reduce<<<dim3(1),    dim3(128), 0, stream>>>(partmax, wmax);
  k2_v2p    <<<dim3(2048), dim3(256), 0, stream>>>(nv2, proj, wmax, v2p);
  k3_v2x    <<<dim3(1024), dim3(256), 0, stream>>>(v2p, x, part, vsumpart);
  k3b_reduce<<<dim3(4160), dim3(256), 0, stream>>>(part, vsumpart, v2x, vsum);
  k4a_v1p   <<<dim3(4096), dim3(256), 0, stream>>>(nv1, proj, v1p);
  k4b_out   <<<dim3(2048), dim3(256), 0, stream>>>(v1p, v2x, vsum, out0);
}

// Round 4
// 1282.474 us; speedup vs baseline: 1.8592x; 1.8592x over previous
//
#include <hip/hip_runtime.h>
#include <math.h>

constexpr int CN = 4096, CHH = 8, CD = 64, CM = 128;
constexpr int V1P_OFF = 16 * 4096 * 8 * 64;             // 33554432 floats
constexpr int V2P_OFF = V1P_OFF + 16 * 4096 * 8 * 128;  // 100663296 floats
constexpr float KSCALE = 0.35355339059327373f;          // 64^-0.25 (tau=1)
constexpr float KRATIO = 0.08838834764831843f;          // 1/sqrt(128)
constexpr float KEPS   = 1e-6f;

__device__ __forceinline__ float dot4(float4 a, float4 b) {
  return fmaf(a.x, b.x, fmaf(a.y, b.y, fmaf(a.z, b.z, a.w * b.w)));
}
__device__ __forceinline__ float4 scl4(float4 a, float s) {
  return make_float4(a.x * s, a.y * s, a.z * s, a.w * s);
}
__device__ __forceinline__ void fma4(float4& a, float s, float4 b) {
  a.x = fmaf(s, b.x, a.x); a.y = fmaf(s, b.y, a.y);
  a.z = fmaf(s, b.z, a.z); a.w = fmaf(s, b.w, a.w);
}
__device__ __forceinline__ float expv(float s, float c) {
  return KRATIO * (__expf(s + c) + KEPS);
}

// ---- K1: per-(b,h) partial max of key data_dash. proj in LDS, 1 row/thread.
__global__ __launch_bounds__(256) void k1_maxdd(
    const float* __restrict__ nv2, const float* __restrict__ proj,
    float* __restrict__ partmax) {
  __shared__ float4 pj[2048];   // proj [128 j][16 f4]
  __shared__ float red[256];
  for (int i = threadIdx.x; i < 2048; i += 256) pj[i] = ((const float4*)proj)[i];
  __syncthreads();
  const int bh = blockIdx.x >> 4, ch = blockIdx.x & 15;
  const int b = bh >> 3, h = bh & 7;
  const int n = ch * 256 + threadIdx.x;
  const float4* a = (const float4*)(nv2 + (size_t)((b * CN + n) * CHH + h) * CD);
  float4 v[16];
#pragma unroll
  for (int q = 0; q < 16; q++) v[q] = scl4(a[q], KSCALE);
  float mx = -1e30f;
  for (int j = 0; j < 128; j += 2) {
    const float4* p0 = &pj[j * 16];
    const float4* p1 = p0 + 16;
    float a0 = 0.f, a1 = 0.f, b0 = 0.f, b1 = 0.f;
#pragma unroll
    for (int q = 0; q < 16; q += 2) {
      a0 += dot4(v[q], p0[q]);     a1 += dot4(v[q + 1], p0[q + 1]);
      b0 += dot4(v[q], p1[q]);     b1 += dot4(v[q + 1], p1[q + 1]);
    }
    mx = fmaxf(mx, fmaxf(a0 + a1, b0 + b1));
  }
  red[threadIdx.x] = mx;
  __syncthreads();
  for (int s = 128; s > 0; s >>= 1) {
    if ((int)threadIdx.x < s) red[threadIdx.x] = fmaxf(red[threadIdx.x], red[threadIdx.x + s]);
    __syncthreads();
  }
  if (threadIdx.x == 0) partmax[blockIdx.x] = red[0];
}

// ---- K1b: reduce 16 partials -> per-bh max
__global__ void k1b_reduce(const float* __restrict__ partmax, float* __restrict__ wmax) {
  const int bh = threadIdx.x;  // 128 threads
  float m = -1e30f;
#pragma unroll
  for (int c = 0; c < 16; c++) m = fmaxf(m, partmax[bh * 16 + c]);
  wmax[bh] = m;
}

// ---- K2: v2p = ratio*(exp(dd - diag - mx_bh)+eps). proj in LDS, 1 row/thread.
__global__ __launch_bounds__(256) void k2_v2p(
    const float* __restrict__ nv2, const float* __restrict__ proj,
    const float* __restrict__ wmax, float* __restrict__ v2p) {
  __shared__ float4 pj[2048];
  for (int i = threadIdx.x; i < 2048; i += 256) pj[i] = ((const float4*)proj)[i];
  __syncthreads();
  const int bh = blockIdx.x >> 4, ch = blockIdx.x & 15;
  const int b = bh >> 3, h = bh & 7;
  const int n = ch * 256 + threadIdx.x;
  const size_t r = (size_t)((b * CN + n) * CHH + h);
  const float4* a = (const float4*)(nv2 + r * CD);
  float4 v[16];
#pragma unroll
  for (int q = 0; q < 16; q++) v[q] = scl4(a[q], KSCALE);
  float diag = 0.f;
#pragma unroll
  for (int q = 0; q < 16; q++) diag += dot4(v[q], v[q]);
  const float c = -(0.5f * diag + wmax[bh]);
  float4* o = (float4*)(v2p + r * CM);
  for (int jb = 0; jb < 4; jb++) {
    float s[32];
#pragma unroll
    for (int jj = 0; jj < 32; jj += 2) {
      const float4* p0 = &pj[(jb * 32 + jj) * 16];
      const float4* p1 = p0 + 16;
      float a0 = 0.f, a1 = 0.f, b0 = 0.f, b1 = 0.f;
#pragma unroll
      for (int q = 0; q < 16; q += 2) {
        a0 += dot4(v[q], p0[q]);     a1 += dot4(v[q + 1], p0[q + 1]);
        b0 += dot4(v[q], p1[q]);     b1 += dot4(v[q + 1], p1[q + 1]);
      }
      s[jj] = a0 + a1; s[jj + 1] = b0 + b1;
    }
#pragma unroll
    for (int jj = 0; jj < 8; jj++)
      o[jb * 8 + jj] = make_float4(expv(s[jj * 4 + 0], c), expv(s[jj * 4 + 1], c),
                                   expv(s[jj * 4 + 2], c), expv(s[jj * 4 + 3], c));
  }
}

// ---- K3: partial v2x = v2p^T @ x. LDS tiles, acc[4 j][8 d] per thread.
__global__ __launch_bounds__(256) void k3_v2x(
    const float* __restrict__ v2p, const float* __restrict__ x,
    float* __restrict__ part, float* __restrict__ vsumpart) {
  __shared__ float4 tv[1024];  // v2p tile [32 n][32 f4 = 128 j]  16KB
  __shared__ float4 tx[512];   // x   tile [32 n][16 f4 = 64 d]    8KB
  const int bh = blockIdx.x >> 3, ch = blockIdx.x & 7;
  const int b = bh >> 3, h = bh & 7;
  const int tj = threadIdx.x >> 3, td = threadIdx.x & 7;  // tj 0..31, td 0..7
  float acc[4][8];
  float vs[4] = {0.f, 0.f, 0.f, 0.f};
#pragma unroll
  for (int i = 0; i < 4; i++)
#pragma unroll
    for (int k = 0; k < 8; k++) acc[i][k] = 0.f;
  for (int t0 = 0; t0 < 512; t0 += 32) {
    const int nb = ch * 512 + t0;
    __syncthreads();
    for (int q = threadIdx.x; q < 1024; q += 256) {
      int nn = q >> 5, c4 = q & 31;
      tv[q] = *((const float4*)(v2p + (size_t)((b * CN + nb + nn) * CHH + h) * CM) + c4);
    }
    for (int q = threadIdx.x; q < 512; q += 256) {
      int nn = q >> 4, c4 = q & 15;
      tx[q] = *((const float4*)(x + (size_t)((b * CN + nb + nn) * CHH + h) * CD) + c4);
    }
    __syncthreads();
    for (int nn = 0; nn < 32; nn++) {
      float4 aa = tv[nn * 32 + tj];
      float4 x0 = tx[nn * 16 + td * 2], x1 = tx[nn * 16 + td * 2 + 1];
      float av[4] = {aa.x, aa.y, aa.z, aa.w};
#pragma unroll
      for (int jj = 0; jj < 4; jj++) {
        acc[jj][0] = fmaf(av[jj], x0.x, acc[jj][0]);
        acc[jj][1] = fmaf(av[jj], x0.y, acc[jj][1]);
        acc[jj][2] = fmaf(av[jj], x0.z, acc[jj][2]);
        acc[jj][3] = fmaf(av[jj], x0.w, acc[jj][3]);
        acc[jj][4] = fmaf(av[jj], x1.x, acc[jj][4]);
        acc[jj][5] = fmaf(av[jj], x1.y, acc[jj][5]);
        acc[jj][6] = fmaf(av[jj], x1.z, acc[jj][6]);
        acc[jj][7] = fmaf(av[jj], x1.w, acc[jj][7]);
      }
      vs[0] += aa.x; vs[1] += aa.y; vs[2] += aa.z; vs[3] += aa.w;
    }
  }
  const size_t pbase = (size_t)blockIdx.x * 8192;
#pragma unroll
  for (int jj = 0; jj < 4; jj++) {
    *(float4*)(part + pbase + (tj * 4 + jj) * 64 + td * 8) =
        make_float4(acc[jj][0], acc[jj][1], acc[jj][2], acc[jj][3]);
    *(float4*)(part + pbase + (tj * 4 + jj) * 64 + td * 8 + 4) =
        make_float4(acc[jj][4], acc[jj][5], acc[jj][6], acc[jj][7]);
  }
  if (td == 0) {
#pragma unroll
    for (int jj = 0; jj < 4; jj++) vsumpart[blockIdx.x * 128 + tj * 4 + jj] = vs[jj];
  }
}

// ---- K3b: reduce 8 partials -> v2x, v2sum  (grid EXACTLY 4160, guarded)
__global__ void k3b_reduce(const float* __restrict__ part, const float* __restrict__ vsumpart,
                           float* __restrict__ v2x, float* __restrict__ vsum) {
  const int i = blockIdx.x * 256 + threadIdx.x;   // covers 1048576 + 16384
  if (i < 1048576) {
    const int bh = i >> 13, r = i & 8191;
    float s = 0.f;
#pragma unroll
    for (int c = 0; c < 8; c++) s += part[(size_t)(bh * 8 + c) * 8192 + r];
    v2x[i] = s;
  } else if (i < 1048576 + 16384) {
    const int k = i - 1048576, bh = k >> 7, j = k & 127;
    float s = 0.f;
#pragma unroll
    for (int c = 0; c < 8; c++) s += vsumpart[(bh * 8 + c) * 128 + j];
    vsum[k] = s;
  }
}

// ---- K4a: v1p. proj in LDS; 2 waves split feature dim; dd[64]+v[64] regs.
__global__ __launch_bounds__(256) void k4a_v1p(
    const float* __restrict__ nv1, const float* __restrict__ proj,
    float* __restrict__ v1p) {
  __shared__ float4 pj[2048];
  __shared__ float hm[2][128];
  for (int i = threadIdx.x; i < 2048; i += 256) pj[i] = ((const float4*)proj)[i];
  __syncthreads();
  const int bh = blockIdx.x >> 5, ch = blockIdx.x & 31;
  const int b = bh >> 3, h = bh & 7;
  const int wave = threadIdx.x >> 6, lane = threadIdx.x & 63;
  const int fh = wave & 1;                        // feature half (wave-uniform)
  const int rloc = (wave >> 1) * 64 + lane;       // 0..127
  const int n = ch * 128 + rloc;
  const size_t r = (size_t)((b * CN + n) * CHH + h);
  const float4* a = (const float4*)(nv1 + r * CD);
  float4 v[16];
#pragma unroll
  for (int q = 0; q < 16; q++) v[q] = scl4(a[q], KSCALE);
  float diag = 0.f;
#pragma unroll
  for (int q = 0; q < 16; q++) diag += dot4(v[q], v[q]);
  float dd[64];
#pragma unroll
  for (int j = 0; j < 64; j += 2) {
    const float4* p0 = &pj[(fh * 64 + j) * 16];
    const float4* p1 = p0 + 16;
    float a0 = 0.f, a1 = 0.f, b0 = 0.f, b1 = 0.f;
#pragma unroll
    for (int q = 0; q < 16; q += 2) {
      a0 += dot4(v[q], p0[q]);     a1 += dot4(v[q + 1], p0[q + 1]);
      b0 += dot4(v[q], p1[q]);     b1 += dot4(v[q + 1], p1[q + 1]);
    }
    dd[j] = a0 + a1; dd[j + 1] = b0 + b1;
  }
  float m0 = -1e30f, m1 = -1e30f, m2 = -1e30f, m3 = -1e30f;
#pragma unroll
  for (int j = 0; j < 64; j += 4) {
    m0 = fmaxf(m0, dd[j]); m1 = fmaxf(m1, dd[j + 1]);
    m2 = fmaxf(m2, dd[j + 2]); m3 = fmaxf(m3, dd[j + 3]);
  }
  hm[fh][rloc] = fmaxf(fmaxf(m0, m1), fmaxf(m2, m3));
  __syncthreads();
  const float c = -(0.5f * diag + fmaxf(hm[0][rloc], hm[1][rloc]));
  float4* o = (float4*)(v1p + r * CM + fh * 64);
#pragma unroll
  for (int q = 0; q < 16; q++)
    o[q] = make_float4(expv(dd[q * 4 + 0], c), expv(dd[q * 4 + 1], c),
                       expv(dd[q * 4 + 2], c), expv(dd[q * 4 + 3], c));
}

// ---- K4b: out0 = (v1p @ v2x) / (v1p . v2sum). v2x + vsum + v1p tiles in LDS.
__global__ __launch_bounds__(256) void k4b_out(
    const float* __restrict__ v1p, const float* __restrict__ v2xg,
    const float* __restrict__ vsumg, float* __restrict__ out0) {
  __shared__ float4 xv[2048];      // v2x [128 j][16 f4]  32KB
  __shared__ float vsh[128];
  __shared__ float tp[256 * 18];   // v1p^T tile [256 rows][16 j] pad 18  18KB
  const int bh = blockIdx.x >> 4, ch = blockIdx.x & 15;
  const int b = bh >> 3, h = bh & 7;
  for (int i = threadIdx.x; i < 2048; i += 256) xv[i] = *((const float4*)v2xg + (size_t)bh * 2048 + i);
  if (threadIdx.x < 128) vsh[threadIdx.x] = vsumg[bh * 128 + threadIdx.x];
  const int nloc = threadIdx.x;
  const int nbase = ch * 256;
  float4 acc4[16];
#pragma unroll
  for (int q = 0; q < 16; q++) acc4[q] = make_float4(0.f, 0.f, 0.f, 0.f);
  float o2 = 0.f;
  for (int jb = 0; jb < 8; jb++) {
    __syncthreads();
    for (int i = threadIdx.x; i < 2048; i += 256) {
      const int row = i >> 3, q = i & 7;  // 8 float2 per row = 16 j
      const float2 t = *((const float2*)(v1p + (size_t)((b * CN + nbase + row) * CHH + h) * CM + jb * 16) + q);
      *(float2*)(&tp[row * 18 + q * 2]) = t;
    }
    __syncthreads();
#pragma unroll
    for (int j = 0; j < 16; j++) {
      const int jg = jb * 16 + j;
      const float p = tp[nloc * 18 + j];
      const float4* xr = &xv[jg * 16];
#pragma unroll
      for (int q = 0; q < 16; q++) fma4(acc4[q], p, xr[q]);
      o2 = fmaf(p, vsh[jg], o2);
    }
  }
  const float inv = 1.0f / o2;
  float4* ob = (float4*)(out0 + (size_t)((b * CN + nbase + nloc) * CHH + h) * CD);
#pragma unroll
  for (int q = 0; q < 16; q++) ob[q] = scl4(acc4[q], inv);
}

extern "C" void kernel_launch(void* const* d_in, const int* in_sizes, int n_in,
                              void* d_out, int out_size, void* d_ws, size_t ws_size,
                              hipStream_t stream) {
  (void)in_sizes; (void)n_in; (void)out_size; (void)ws_size;
  const float* x    = (const float*)d_in[0];
  const float* nv1  = (const float*)d_in[1];
  const float* nv2  = (const float*)d_in[2];
  const float* proj = (const float*)d_in[3];
  float* out  = (float*)d_out;
  float* out0 = out;
  float* v1p  = out + V1P_OFF;
  float* v2p  = out + V2P_OFF;

  // Scratch inside the v1p output region (dead before k4a writes v1p):
  float* part     = v1p;                  // 1024*8192 = 8,388,608 floats
  float* partmax  = v1p + 8388608;        // 2,048
  float* vsumpart = v1p + 8390656;        // 1024*128 = 131,072
  // Persistent scratch in ws (~4.3 MB): survives into k4b.
  float* ws   = (float*)d_ws;
  float* wmax = ws;                       // 128
  float* vsum = ws + 128;                 // 16,384
  float* v2x  = ws + 16512;               // 1,048,576

  k1_maxdd  <<<dim3(2048), dim3(256), 0, stream>>>(nv2, proj, partmax);
  k1b_reduce<<<dim3(1),    dim3(128), 0, stream>>>(partmax, wmax);
  k2_v2p    <<<dim3(2048), dim3(256), 0, stream>>>(nv2, proj, wmax, v2p);
  k3_v2x    <<<dim3(1024), dim3(256), 0, stream>>>(v2p, x, part, vsumpart);
  k3b_reduce<<<dim3(4160), dim3(256), 0, stream>>>(part, vsumpart, v2x, vsum);
  k4a_v1p   <<<dim3(4096), dim3(256), 0, stream>>>(nv1, proj, v1p);
  k4b_out   <<<dim3(2048), dim3(256), 0, stream>>>(v1p, v2x, vsum, out0);
}

// Round 5
// 1029.864 us; speedup vs baseline: 2.3152x; 1.2453x over previous
//
#include <hip/hip_runtime.h>
#include <math.h>

constexpr int CN = 4096, CHH = 8, CD = 64, CM = 128;
constexpr int V1P_OFF = 16 * 4096 * 8 * 64;             // 33554432 floats
constexpr int V2P_OFF = V1P_OFF + 16 * 4096 * 8 * 128;  // 100663296 floats
constexpr float KSCALE = 0.35355339059327373f;          // 64^-0.25 (tau=1)
constexpr float KRATIO = 0.08838834764831843f;          // 1/sqrt(128)
constexpr float KEPS   = 1e-6f;

__device__ __forceinline__ float dot4(float4 a, float4 b) {
  return fmaf(a.x, b.x, fmaf(a.y, b.y, fmaf(a.z, b.z, a.w * b.w)));
}
__device__ __forceinline__ float4 scl4(float4 a, float s) {
  return make_float4(a.x * s, a.y * s, a.z * s, a.w * s);
}
__device__ __forceinline__ void fma4(float4& a, float s, float4 b) {
  a.x = fmaf(s, b.x, a.x); a.y = fmaf(s, b.y, a.y);
  a.z = fmaf(s, b.z, a.z); a.w = fmaf(s, b.w, a.w);
}
__device__ __forceinline__ float expv(float s, float c) {
  return KRATIO * (__expf(s + c) + KEPS);
}

// ---- K2e: e = exp(dd - diag) (unshifted) + per-block raw-dd max.
//      R=2 rows/thread (proj read shared), j-chunks of 8. ~165 VGPR.
__global__ __launch_bounds__(256) void k2e(
    const float* __restrict__ nv2, const float* __restrict__ proj,
    float* __restrict__ e_out, float* __restrict__ partmax) {
  __shared__ float4 pj[2048];   // proj [128 j][16 f4] 32KB
  __shared__ float red[256];
  for (int i = threadIdx.x; i < 2048; i += 256) pj[i] = ((const float4*)proj)[i];
  __syncthreads();
  const int bh = blockIdx.x >> 3, ch = blockIdx.x & 7;
  const int b = bh >> 3, h = bh & 7;
  const int n0 = ch * 512 + threadIdx.x;          // rows n0, n0+256
  const size_t r0 = (size_t)((b * CN + n0) * CHH + h);
  const size_t r1 = (size_t)((b * CN + n0 + 256) * CHH + h);
  const float4* a0 = (const float4*)(nv2 + r0 * CD);
  const float4* a1 = (const float4*)(nv2 + r1 * CD);
  float4 v0[16], v1[16];
#pragma unroll
  for (int q = 0; q < 16; q++) { v0[q] = scl4(a0[q], KSCALE); v1[q] = scl4(a1[q], KSCALE); }
  float d0 = 0.f, d1 = 0.f;
#pragma unroll
  for (int q = 0; q < 16; q++) { d0 += dot4(v0[q], v0[q]); d1 += dot4(v1[q], v1[q]); }
  const float c0 = -0.5f * d0, c1 = -0.5f * d1;   // NO max shift here
  float4* o0 = (float4*)(e_out + r0 * CM);
  float4* o1 = (float4*)(e_out + r1 * CM);
  float mx = -1e30f;
  for (int jb = 0; jb < 16; jb++) {               // 16 chunks x 8 j
    float s0[8], s1[8];
#pragma unroll
    for (int jj = 0; jj < 8; jj++) {
      const float4* p = &pj[(jb * 8 + jj) * 16];
      float a0s = 0.f, a1s = 0.f, b0s = 0.f, b1s = 0.f;
#pragma unroll
      for (int q = 0; q < 16; q += 2) {
        float4 pa = p[q], pb = p[q + 1];
        a0s += dot4(v0[q], pa); a1s += dot4(v0[q + 1], pb);
        b0s += dot4(v1[q], pa); b1s += dot4(v1[q + 1], pb);
      }
      s0[jj] = a0s + a1s; s1[jj] = b0s + b1s;
      mx = fmaxf(mx, fmaxf(s0[jj], s1[jj]));
    }
#pragma unroll
    for (int u = 0; u < 2; u++) {
      o0[jb * 2 + u] = make_float4(__expf(s0[u * 4 + 0] + c0), __expf(s0[u * 4 + 1] + c0),
                                   __expf(s0[u * 4 + 2] + c0), __expf(s0[u * 4 + 3] + c0));
      o1[jb * 2 + u] = make_float4(__expf(s1[u * 4 + 0] + c1), __expf(s1[u * 4 + 1] + c1),
                                   __expf(s1[u * 4 + 2] + c1), __expf(s1[u * 4 + 3] + c1));
    }
  }
  red[threadIdx.x] = mx;
  __syncthreads();
  for (int s = 128; s > 0; s >>= 1) {
    if ((int)threadIdx.x < s) red[threadIdx.x] = fmaxf(red[threadIdx.x], red[threadIdx.x + s]);
    __syncthreads();
  }
  if (threadIdx.x == 0) partmax[blockIdx.x] = red[0];
}

// ---- K2b: per-bh scale factor s = exp(-max)
__global__ void k2b_scale(const float* __restrict__ partmax, float* __restrict__ sfac) {
  const int bh = threadIdx.x;  // 128 threads
  float m = -1e30f;
#pragma unroll
  for (int c = 0; c < 8; c++) m = fmaxf(m, partmax[bh * 8 + c]);
  sfac[bh] = __expf(-m);
}

// ---- K3v: v2p = ratio*(e*s + eps) (written out) + partial v2x GEMM.
//      Reg-prefetch double-buffered LDS tiles.
__global__ __launch_bounds__(256) void k3v(
    const float* __restrict__ e_in, const float* __restrict__ x,
    const float* __restrict__ sfac, float* __restrict__ v2p_out,
    float* __restrict__ part, float* __restrict__ vsumpart) {
  __shared__ float4 tv[1024];  // v2p tile [32 n][32 f4 = 128 j] 16KB
  __shared__ float4 tx[512];   // x   tile [32 n][16 f4 =  64 d]  8KB
  const int bh = blockIdx.x >> 3, ch = blockIdx.x & 7;
  const int b = bh >> 3, h = bh & 7;
  const float ss = KRATIO * sfac[bh];
  const float rk = KRATIO * KEPS;
  const int tj = threadIdx.x >> 3, td = threadIdx.x & 7;  // tj 0..31, td 0..7
  float acc[4][8];
  float vs[4] = {0.f, 0.f, 0.f, 0.f};
#pragma unroll
  for (int i = 0; i < 4; i++)
#pragma unroll
    for (int k = 0; k < 8; k++) acc[i][k] = 0.f;
  float4 rv[4], rx[2];
  // prefetch tile 0 (scale e -> v2p, write back final v2p, keep in regs)
  {
    const int nb = ch * 512;
#pragma unroll
    for (int k = 0; k < 4; k++) {
      const int q = threadIdx.x + k * 256, nn = q >> 5, c4 = q & 31;
      const size_t r = (size_t)((b * CN + nb + nn) * CHH + h);
      float4 ev = *((const float4*)(e_in + r * CM) + c4);
      float4 sv = make_float4(fmaf(ev.x, ss, rk), fmaf(ev.y, ss, rk),
                              fmaf(ev.z, ss, rk), fmaf(ev.w, ss, rk));
      *((float4*)(v2p_out + r * CM) + c4) = sv;
      rv[k] = sv;
    }
#pragma unroll
    for (int k = 0; k < 2; k++) {
      const int q = threadIdx.x + k * 256, nn = q >> 4, c4 = q & 15;
      rx[k] = *((const float4*)(x + (size_t)((b * CN + nb + nn) * CHH + h) * CD) + c4);
    }
  }
  for (int t = 0; t < 16; t++) {
    __syncthreads();
#pragma unroll
    for (int k = 0; k < 4; k++) tv[threadIdx.x + k * 256] = rv[k];
#pragma unroll
    for (int k = 0; k < 2; k++) tx[threadIdx.x + k * 256] = rx[k];
    __syncthreads();
    if (t < 15) {  // issue next-tile loads; latency hides under compute below
      const int nb = ch * 512 + (t + 1) * 32;
#pragma unroll
      for (int k = 0; k < 4; k++) {
        const int q = threadIdx.x + k * 256, nn = q >> 5, c4 = q & 31;
        const size_t r = (size_t)((b * CN + nb + nn) * CHH + h);
        float4 ev = *((const float4*)(e_in + r * CM) + c4);
        float4 sv = make_float4(fmaf(ev.x, ss, rk), fmaf(ev.y, ss, rk),
                                fmaf(ev.z, ss, rk), fmaf(ev.w, ss, rk));
        *((float4*)(v2p_out + r * CM) + c4) = sv;
        rv[k] = sv;
      }
#pragma unroll
      for (int k = 0; k < 2; k++) {
        const int q = threadIdx.x + k * 256, nn = q >> 4, c4 = q & 15;
        rx[k] = *((const float4*)(x + (size_t)((b * CN + nb + nn) * CHH + h) * CD) + c4);
      }
    }
    for (int nn = 0; nn < 32; nn++) {
      float4 aa = tv[nn * 32 + tj];
      float4 x0 = tx[nn * 16 + td * 2], x1 = tx[nn * 16 + td * 2 + 1];
      float av[4] = {aa.x, aa.y, aa.z, aa.w};
#pragma unroll
      for (int jj = 0; jj < 4; jj++) {
        acc[jj][0] = fmaf(av[jj], x0.x, acc[jj][0]);
        acc[jj][1] = fmaf(av[jj], x0.y, acc[jj][1]);
        acc[jj][2] = fmaf(av[jj], x0.z, acc[jj][2]);
        acc[jj][3] = fmaf(av[jj], x0.w, acc[jj][3]);
        acc[jj][4] = fmaf(av[jj], x1.x, acc[jj][4]);
        acc[jj][5] = fmaf(av[jj], x1.y, acc[jj][5]);
        acc[jj][6] = fmaf(av[jj], x1.z, acc[jj][6]);
        acc[jj][7] = fmaf(av[jj], x1.w, acc[jj][7]);
      }
      vs[0] += aa.x; vs[1] += aa.y; vs[2] += aa.z; vs[3] += aa.w;
    }
  }
  const size_t pbase = (size_t)blockIdx.x * 8192;
#pragma unroll
  for (int jj = 0; jj < 4; jj++) {
    *(float4*)(part + pbase + (tj * 4 + jj) * 64 + td * 8) =
        make_float4(acc[jj][0], acc[jj][1], acc[jj][2], acc[jj][3]);
    *(float4*)(part + pbase + (tj * 4 + jj) * 64 + td * 8 + 4) =
        make_float4(acc[jj][4], acc[jj][5], acc[jj][6], acc[jj][7]);
  }
  if (td == 0) {
#pragma unroll
    for (int jj = 0; jj < 4; jj++) vsumpart[blockIdx.x * 128 + tj * 4 + jj] = vs[jj];
  }
}

// ---- K3b: reduce 8 partials -> v2x, v2sum  (grid EXACTLY 4160, guarded)
__global__ void k3b_reduce(const float* __restrict__ part, const float* __restrict__ vsumpart,
                           float* __restrict__ v2x, float* __restrict__ vsum) {
  const int i = blockIdx.x * 256 + threadIdx.x;   // covers 1048576 + 16384
  if (i < 1048576) {
    const int bh = i >> 13, r = i & 8191;
    float s = 0.f;
#pragma unroll
    for (int c = 0; c < 8; c++) s += part[(size_t)(bh * 8 + c) * 8192 + r];
    v2x[i] = s;
  } else if (i < 1048576 + 16384) {
    const int k = i - 1048576, bh = k >> 7, j = k & 127;
    float s = 0.f;
#pragma unroll
    for (int c = 0; c < 8; c++) s += vsumpart[(bh * 8 + c) * 128 + j];
    vsum[k] = s;
  }
}

// ---- K4a: v1p. proj in LDS; 2 waves split feature dim; dd[64]+v[64] regs.
__global__ __launch_bounds__(256) void k4a_v1p(
    const float* __restrict__ nv1, const float* __restrict__ proj,
    float* __restrict__ v1p) {
  __shared__ float4 pj[2048];
  __shared__ float hm[2][128];
  for (int i = threadIdx.x; i < 2048; i += 256) pj[i] = ((const float4*)proj)[i];
  __syncthreads();
  const int bh = blockIdx.x >> 5, ch = blockIdx.x & 31;
  const int b = bh >> 3, h = bh & 7;
  const int wave = threadIdx.x >> 6, lane = threadIdx.x & 63;
  const int fh = wave & 1;                        // feature half (wave-uniform)
  const int rloc = (wave >> 1) * 64 + lane;       // 0..127
  const int n = ch * 128 + rloc;
  const size_t r = (size_t)((b * CN + n) * CHH + h);
  const float4* a = (const float4*)(nv1 + r * CD);
  float4 v[16];
#pragma unroll
  for (int q = 0; q < 16; q++) v[q] = scl4(a[q], KSCALE);
  float diag = 0.f;
#pragma unroll
  for (int q = 0; q < 16; q++) diag += dot4(v[q], v[q]);
  float dd[64];
#pragma unroll
  for (int j = 0; j < 64; j += 2) {
    const float4* p0 = &pj[(fh * 64 + j) * 16];
    const float4* p1 = p0 + 16;
    float a0 = 0.f, a1 = 0.f, b0 = 0.f, b1 = 0.f;
#pragma unroll
    for (int q = 0; q < 16; q += 2) {
      a0 += dot4(v[q], p0[q]);     a1 += dot4(v[q + 1], p0[q + 1]);
      b0 += dot4(v[q], p1[q]);     b1 += dot4(v[q + 1], p1[q + 1]);
    }
    dd[j] = a0 + a1; dd[j + 1] = b0 + b1;
  }
  float m0 = -1e30f, m1 = -1e30f, m2 = -1e30f, m3 = -1e30f;
#pragma unroll
  for (int j = 0; j < 64; j += 4) {
    m0 = fmaxf(m0, dd[j]); m1 = fmaxf(m1, dd[j + 1]);
    m2 = fmaxf(m2, dd[j + 2]); m3 = fmaxf(m3, dd[j + 3]);
  }
  hm[fh][rloc] = fmaxf(fmaxf(m0, m1), fmaxf(m2, m3));
  __syncthreads();
  const float c = -(0.5f * diag + fmaxf(hm[0][rloc], hm[1][rloc]));
  float4* o = (float4*)(v1p + r * CM + fh * 64);
#pragma unroll
  for (int q = 0; q < 16; q++)
    o[q] = make_float4(expv(dd[q * 4 + 0], c), expv(dd[q * 4 + 1], c),
                       expv(dd[q * 4 + 2], c), expv(dd[q * 4 + 3], c));
}

// ---- K4b: out0 = (v1p @ v2x) / (v1p . v2sum). v2x + vsum + v1p tiles in LDS.
__global__ __launch_bounds__(256) void k4b_out(
    const float* __restrict__ v1p, const float* __restrict__ v2xg,
    const float* __restrict__ vsumg, float* __restrict__ out0) {
  __shared__ float4 xv[2048];      // v2x [128 j][16 f4]  32KB
  __shared__ float vsh[128];
  __shared__ float tp[256 * 18];   // v1p^T tile [256 rows][16 j] pad 18  18KB
  const int bh = blockIdx.x >> 4, ch = blockIdx.x & 15;
  const int b = bh >> 3, h = bh & 7;
  for (int i = threadIdx.x; i < 2048; i += 256) xv[i] = *((const float4*)v2xg + (size_t)bh * 2048 + i);
  if (threadIdx.x < 128) vsh[threadIdx.x] = vsumg[bh * 128 + threadIdx.x];
  const int nloc = threadIdx.x;
  const int nbase = ch * 256;
  float4 acc4[16];
#pragma unroll
  for (int q = 0; q < 16; q++) acc4[q] = make_float4(0.f, 0.f, 0.f, 0.f);
  float o2 = 0.f;
  for (int jb = 0; jb < 8; jb++) {
    __syncthreads();
    for (int i = threadIdx.x; i < 2048; i += 256) {
      const int row = i >> 3, q = i & 7;  // 8 float2 per row = 16 j
      const float2 t = *((const float2*)(v1p + (size_t)((b * CN + nbase + row) * CHH + h) * CM + jb * 16) + q);
      *(float2*)(&tp[row * 18 + q * 2]) = t;
    }
    __syncthreads();
#pragma unroll
    for (int j = 0; j < 16; j++) {
      const int jg = jb * 16 + j;
      const float p = tp[nloc * 18 + j];
      const float4* xr = &xv[jg * 16];
#pragma unroll
      for (int q = 0; q < 16; q++) fma4(acc4[q], p, xr[q]);
      o2 = fmaf(p, vsh[jg], o2);
    }
  }
  const float inv = 1.0f / o2;
  float4* ob = (float4*)(out0 + (size_t)((b * CN + nbase + nloc) * CHH + h) * CD);
#pragma unroll
  for (int q = 0; q < 16; q++) ob[q] = scl4(acc4[q], inv);
}

extern "C" void kernel_launch(void* const* d_in, const int* in_sizes, int n_in,
                              void* d_out, int out_size, void* d_ws, size_t ws_size,
                              hipStream_t stream) {
  (void)in_sizes; (void)n_in; (void)out_size; (void)ws_size;
  const float* x    = (const float*)d_in[0];
  const float* nv1  = (const float*)d_in[1];
  const float* nv2  = (const float*)d_in[2];
  const float* proj = (const float*)d_in[3];
  float* out  = (float*)d_out;
  float* out0 = out;
  float* v1p  = out + V1P_OFF;
  float* v2p  = out + V2P_OFF;

  // Scratch inside the v1p output region (dead before k4a writes v1p):
  float* part     = v1p;                  // 1024*8192 = 8,388,608 floats
  float* partmax  = v1p + 8388608;        // 1,024
  float* vsumpart = v1p + 8389632;        // 1024*128 = 131,072
  // Persistent scratch in ws (~4.3 MB): survives into k4b.
  float* ws   = (float*)d_ws;
  float* sfac = ws;                       // 128
  float* vsum = ws + 128;                 // 16,384
  float* v2x  = ws + 16512;               // 1,048,576

  k2e      <<<dim3(1024), dim3(256), 0, stream>>>(nv2, proj, v2p, partmax);
  k2b_scale<<<dim3(1),    dim3(128), 0, stream>>>(partmax, sfac);
  k3v      <<<dim3(1024), dim3(256), 0, stream>>>(v2p, x, sfac, v2p, part, vsumpart);
  k3b_reduce<<<dim3(4160),dim3(256), 0, stream>>>(part, vsumpart, v2x, vsum);
  k4a_v1p  <<<dim3(4096), dim3(256), 0, stream>>>(nv1, proj, v1p);
  k4b_out  <<<dim3(2048), dim3(256), 0, stream>>>(v1p, v2x, vsum, out0);
}